// Round 1
// baseline (1104.254 us; speedup 1.0000x reference)
//
#include <hip/hip_runtime.h>
#include <hip/hip_bf16.h>
#include <stdint.h>

typedef __bf16 bf16;
typedef __bf16 bf16x8 __attribute__((ext_vector_type(8)));
typedef float floatx4 __attribute__((ext_vector_type(4)));

#define T_TOK 8192
#define DIM 2048
#define NE 8

// ---- async global->LDS 16B (m97 pattern) ----
__device__ inline void gld_lds16(const bf16* g, bf16* l) {
  __builtin_amdgcn_global_load_lds(
      (const __attribute__((address_space(1))) uint32_t*)g,
      (__attribute__((address_space(3))) uint32_t*)l, 16, 0, 0);
}

// ---- transpose [Dk,Dn] fp32 -> [Dn,Dk] bf16, batched over blockIdx.z ----
__global__ __launch_bounds__(256) void transpose_convert(
    const float* __restrict__ in, bf16* __restrict__ out) {
  __shared__ float tile[32][33];
  const int tx = threadIdx.x & 31;
  const int ty = threadIdx.x >> 5;
  const int n0 = blockIdx.x * 32;
  const int k0 = blockIdx.y * 32;
  const size_t base = (size_t)blockIdx.z * DIM * DIM;
  const float* src = in + base;
  bf16* dst = out + base;
#pragma unroll
  for (int i = 0; i < 32; i += 8)
    tile[ty + i][tx] = src[(size_t)(k0 + ty + i) * DIM + n0 + tx];
  __syncthreads();
#pragma unroll
  for (int i = 0; i < 32; i += 8)
    dst[(size_t)(n0 + ty + i) * DIM + k0 + tx] = (bf16)tile[tx][ty + i];
}

// ---- router: logits, top-2 (strict >, lower index on ties), softmax gates,
//      scatter (assign_id, gate) into per-expert lists ----
__global__ __launch_bounds__(256) void router_kernel(
    const float* __restrict__ x, const float* __restrict__ Wr,
    const float* __restrict__ br, int* __restrict__ cnt,
    int* __restrict__ aid_list, float* __restrict__ gate_list) {
  const int t = blockIdx.x;
  const int tid = threadIdx.x;
  const float* xr = x + (size_t)t * DIM;
  float acc[8];
#pragma unroll
  for (int e = 0; e < 8; ++e) acc[e] = 0.f;
#pragma unroll
  for (int h = 0; h < 2; ++h) {
    const int d0 = tid * 4 + h * 1024;
    float4 xv = *(const float4*)&xr[d0];
    const float* wp = &Wr[(size_t)d0 * NE];
    float xe[4] = {xv.x, xv.y, xv.z, xv.w};
#pragma unroll
    for (int q = 0; q < 4; ++q) {
      float4 w0 = *(const float4*)&wp[q * 8];
      float4 w1 = *(const float4*)&wp[q * 8 + 4];
      acc[0] += xe[q] * w0.x; acc[1] += xe[q] * w0.y;
      acc[2] += xe[q] * w0.z; acc[3] += xe[q] * w0.w;
      acc[4] += xe[q] * w1.x; acc[5] += xe[q] * w1.y;
      acc[6] += xe[q] * w1.z; acc[7] += xe[q] * w1.w;
    }
  }
#pragma unroll
  for (int e = 0; e < 8; ++e) {
#pragma unroll
    for (int off = 32; off > 0; off >>= 1) acc[e] += __shfl_down(acc[e], off, 64);
  }
  __shared__ float red[4][8];
  const int lane = tid & 63, wid = tid >> 6;
  if (lane == 0) {
#pragma unroll
    for (int e = 0; e < 8; ++e) red[wid][e] = acc[e];
  }
  __syncthreads();
  if (tid == 0) {
    float lg[8];
#pragma unroll
    for (int e = 0; e < 8; ++e)
      lg[e] = red[0][e] + red[1][e] + red[2][e] + red[3][e] + br[e];
    int i0 = 0;
#pragma unroll
    for (int e = 1; e < 8; ++e) if (lg[e] > lg[i0]) i0 = e;
    int i1 = (i0 == 0) ? 1 : 0;
#pragma unroll
    for (int e = 0; e < 8; ++e)
      if (e != i0 && lg[e] > lg[i1]) i1 = e;
    const float g0 = 1.f / (1.f + expf(lg[i1] - lg[i0]));
    const float g1 = 1.f - g0;
    int p0 = atomicAdd(&cnt[i0], 1);
    aid_list[i0 * T_TOK + p0] = t * 2;
    gate_list[i0 * T_TOK + p0] = g0;
    int p1 = atomicAdd(&cnt[i1], 1);
    aid_list[i1 * T_TOK + p1] = t * 2 + 1;
    gate_list[i1 * T_TOK + p1] = g1;
  }
}

// ---- grouped expert GEMM: H = silu(Xg @ We[e] + be[e]) * gate, scatter to
//      per-assignment rows (bf16). 128x128 tile, 4 waves x 4x4 mfma 16x16x32 ----
__global__ __launch_bounds__(256, 2) void expert_gemm(
    const float* __restrict__ x, const bf16* __restrict__ Wt,
    const float* __restrict__ be, const int* __restrict__ cnt,
    const int* __restrict__ aid_list, const float* __restrict__ gate_list,
    bf16* __restrict__ aout) {
  const int e = blockIdx.z;
  const int ne = cnt[e];
  const int m0 = blockIdx.x * 128;
  if (m0 >= ne) return;
  const int n0 = blockIdx.y * 128;
  const int tid = threadIdx.x;

  __shared__ bf16 As[128][32];
  __shared__ bf16 Bs[128][32];
  __shared__ int aidS[128];
  __shared__ float gateS[128];

  if (tid < 128) {
    const int idx = m0 + tid;
    if (idx < ne) {
      aidS[tid] = aid_list[e * T_TOK + idx];
      gateS[tid] = gate_list[e * T_TOK + idx];
    } else {
      aidS[tid] = 0;      // rows >= ne compute garbage but are never stored
      gateS[tid] = 0.f;
    }
  }
  __syncthreads();

  const int lane = tid & 63, wid = tid >> 6;
  const int wr = (wid >> 1) * 64, wc = (wid & 1) * 64;
  const int quad = lane >> 4, l15 = lane & 15;

  floatx4 acc[4][4];
#pragma unroll
  for (int i = 0; i < 4; ++i)
#pragma unroll
    for (int j = 0; j < 4; ++j) acc[i][j] = (floatx4){0.f, 0.f, 0.f, 0.f};

  const int ar = tid >> 1;
  const int akq = (tid & 1) * 16;
  const size_t xrow = (size_t)(aidS[ar] >> 1) * DIM + akq;
  const bf16* wbase = Wt + (size_t)e * DIM * DIM;

  for (int k0 = 0; k0 < DIM; k0 += 32) {
    // B tile: async 16B direct-to-LDS, layout Bs[n][k] (k contiguous)
#pragma unroll
    for (int h = 0; h < 2; ++h) {
      const int c = tid + h * 256;
      const int bn = c >> 2, bk = (c & 3) * 8;
      gld_lds16(wbase + (size_t)(n0 + bn) * DIM + k0 + bk, &Bs[0][0] + c * 8);
    }
    // A tile: gathered fp32 row -> bf16
    const float* xp = x + xrow + k0;
    float4 f0 = *(const float4*)(xp);
    float4 f1 = *(const float4*)(xp + 4);
    float4 f2 = *(const float4*)(xp + 8);
    float4 f3 = *(const float4*)(xp + 12);
    bf16x8 v0, v1;
    v0[0] = (bf16)f0.x; v0[1] = (bf16)f0.y; v0[2] = (bf16)f0.z; v0[3] = (bf16)f0.w;
    v0[4] = (bf16)f1.x; v0[5] = (bf16)f1.y; v0[6] = (bf16)f1.z; v0[7] = (bf16)f1.w;
    v1[0] = (bf16)f2.x; v1[1] = (bf16)f2.y; v1[2] = (bf16)f2.z; v1[3] = (bf16)f2.w;
    v1[4] = (bf16)f3.x; v1[5] = (bf16)f3.y; v1[6] = (bf16)f3.z; v1[7] = (bf16)f3.w;
    *(bf16x8*)&As[ar][akq] = v0;
    *(bf16x8*)&As[ar][akq + 8] = v1;
    __syncthreads();

    bf16x8 af[4], bfr[4];
#pragma unroll
    for (int i = 0; i < 4; ++i)
      af[i] = *(const bf16x8*)&As[wr + i * 16 + l15][quad * 8];
#pragma unroll
    for (int j = 0; j < 4; ++j)
      bfr[j] = *(const bf16x8*)&Bs[wc + j * 16 + l15][quad * 8];
#pragma unroll
    for (int i = 0; i < 4; ++i)
#pragma unroll
      for (int j = 0; j < 4; ++j)
        acc[i][j] = __builtin_amdgcn_mfma_f32_16x16x32_bf16(af[i], bfr[j], acc[i][j], 0, 0, 0);
    __syncthreads();
  }

  // epilogue: + be, silu, * gate, scatter bf16 to assignment row
#pragma unroll
  for (int j = 0; j < 4; ++j) {
    const int col = n0 + wc + j * 16 + l15;
    const float bev = be[e * DIM + col];
#pragma unroll
    for (int i = 0; i < 4; ++i) {
#pragma unroll
      for (int r = 0; r < 4; ++r) {
        const int rl = wr + i * 16 + quad * 4 + r;
        if (m0 + rl < ne) {
          float v = acc[i][j][r] + bev;
          v = v / (1.f + __expf(-v));
          v *= gateS[rl];
          aout[(size_t)aidS[rl] * DIM + col] = (bf16)v;
        }
      }
    }
  }
}

// ---- output projection: (slot0+slot1) @ Wo + bo + x -> y (fp32, into d_out) ----
__global__ __launch_bounds__(256, 2) void proj_gemm(
    const bf16* __restrict__ aout, const bf16* __restrict__ Wot,
    const float* __restrict__ bo, const float* __restrict__ x,
    float* __restrict__ y) {
  const int m0 = blockIdx.x * 128;
  const int n0 = blockIdx.y * 128;
  const int tid = threadIdx.x;

  __shared__ bf16 As[128][32];
  __shared__ bf16 Bs[128][32];

  const int lane = tid & 63, wid = tid >> 6;
  const int wr = (wid >> 1) * 64, wc = (wid & 1) * 64;
  const int quad = lane >> 4, l15 = lane & 15;

  floatx4 acc[4][4];
#pragma unroll
  for (int i = 0; i < 4; ++i)
#pragma unroll
    for (int j = 0; j < 4; ++j) acc[i][j] = (floatx4){0.f, 0.f, 0.f, 0.f};

  const int ar = tid >> 1;
  const int akq = (tid & 1) * 16;
  const size_t r0 = (size_t)(m0 + ar) * 2 * DIM + akq;  // slot0 row of token

  for (int k0 = 0; k0 < DIM; k0 += 32) {
#pragma unroll
    for (int h = 0; h < 2; ++h) {
      const int c = tid + h * 256;
      const int bn = c >> 2, bk = (c & 3) * 8;
      gld_lds16(Wot + (size_t)(n0 + bn) * DIM + k0 + bk, &Bs[0][0] + c * 8);
    }
#pragma unroll
    for (int h = 0; h < 2; ++h) {
      bf16x8 u0 = *(const bf16x8*)&aout[r0 + k0 + h * 8];
      bf16x8 u1 = *(const bf16x8*)&aout[r0 + DIM + k0 + h * 8];
      bf16x8 s;
#pragma unroll
      for (int q = 0; q < 8; ++q) s[q] = (bf16)((float)u0[q] + (float)u1[q]);
      *(bf16x8*)&As[ar][akq + h * 8] = s;
    }
    __syncthreads();

    bf16x8 af[4], bfr[4];
#pragma unroll
    for (int i = 0; i < 4; ++i)
      af[i] = *(const bf16x8*)&As[wr + i * 16 + l15][quad * 8];
#pragma unroll
    for (int j = 0; j < 4; ++j)
      bfr[j] = *(const bf16x8*)&Bs[wc + j * 16 + l15][quad * 8];
#pragma unroll
    for (int i = 0; i < 4; ++i)
#pragma unroll
      for (int j = 0; j < 4; ++j)
        acc[i][j] = __builtin_amdgcn_mfma_f32_16x16x32_bf16(af[i], bfr[j], acc[i][j], 0, 0, 0);
    __syncthreads();
  }

#pragma unroll
  for (int j = 0; j < 4; ++j) {
    const int col = n0 + wc + j * 16 + l15;
    const float bov = bo[col];
#pragma unroll
    for (int i = 0; i < 4; ++i) {
#pragma unroll
      for (int r = 0; r < 4; ++r) {
        const int rl = wr + i * 16 + quad * 4 + r;
        const size_t o = (size_t)(m0 + rl) * DIM + col;
        y[o] = acc[i][j][r] + bov + x[o];
      }
    }
  }
}

// ---- in-place RMSNorm over rows of d_out ----
__global__ __launch_bounds__(256) void rmsnorm_kernel(
    float* __restrict__ y, const float* __restrict__ w) {
  const int row = blockIdx.x;
  const int tid = threadIdx.x;
  float* yr = y + (size_t)row * DIM;
  float4 v0 = ((const float4*)yr)[tid];
  float4 v1 = ((const float4*)yr)[tid + 256];
  float ss = v0.x * v0.x + v0.y * v0.y + v0.z * v0.z + v0.w * v0.w +
             v1.x * v1.x + v1.y * v1.y + v1.z * v1.z + v1.w * v1.w;
#pragma unroll
  for (int off = 32; off > 0; off >>= 1) ss += __shfl_down(ss, off, 64);
  __shared__ float s4[4];
  const int lane = tid & 63, wid = tid >> 6;
  if (lane == 0) s4[wid] = ss;
  __syncthreads();
  const float tot = s4[0] + s4[1] + s4[2] + s4[3];
  const float r = rsqrtf(tot / (float)DIM + 1e-6f);
  float4 w0 = ((const float4*)w)[tid];
  float4 w1 = ((const float4*)w)[tid + 256];
  float4 o0 = make_float4(v0.x * r * w0.x, v0.y * r * w0.y, v0.z * r * w0.z, v0.w * r * w0.w);
  float4 o1 = make_float4(v1.x * r * w1.x, v1.y * r * w1.y, v1.z * r * w1.z, v1.w * r * w1.w);
  ((float4*)yr)[tid] = o0;
  ((float4*)yr)[tid + 256] = o1;
}

extern "C" void kernel_launch(void* const* d_in, const int* in_sizes, int n_in,
                              void* d_out, int out_size, void* d_ws, size_t ws_size,
                              hipStream_t stream) {
  const float* x  = (const float*)d_in[0];
  const float* Wr = (const float*)d_in[1];
  const float* br = (const float*)d_in[2];
  const float* We = (const float*)d_in[3];
  const float* be = (const float*)d_in[4];
  const float* Wo = (const float*)d_in[5];
  const float* bo = (const float*)d_in[6];
  const float* nw = (const float*)d_in[7];
  float* out = (float*)d_out;

  uint8_t* ws = (uint8_t*)d_ws;
  size_t off = 0;
  auto carve = [&](size_t bytes) -> void* {
    void* p = ws + off;
    off += (bytes + 255) & ~(size_t)255;
    return p;
  };
  int*   cnt       = (int*)carve(NE * sizeof(int));
  int*   aid_list  = (int*)carve((size_t)NE * T_TOK * sizeof(int));
  float* gate_list = (float*)carve((size_t)NE * T_TOK * sizeof(float));
  bf16*  We_t      = (bf16*)carve((size_t)NE * DIM * DIM * sizeof(bf16));
  bf16*  Wo_t      = (bf16*)carve((size_t)DIM * DIM * sizeof(bf16));
  bf16*  aoutb     = (bf16*)carve((size_t)T_TOK * 2 * DIM * sizeof(bf16));
  (void)ws_size; (void)in_sizes; (void)n_in; (void)out_size;

  hipMemsetAsync(cnt, 0, NE * sizeof(int), stream);
  transpose_convert<<<dim3(DIM / 32, DIM / 32, NE), 256, 0, stream>>>(We, We_t);
  transpose_convert<<<dim3(DIM / 32, DIM / 32, 1), 256, 0, stream>>>(Wo, Wo_t);
  router_kernel<<<T_TOK, 256, 0, stream>>>(x, Wr, br, cnt, aid_list, gate_list);
  expert_gemm<<<dim3(T_TOK / 128, DIM / 128, NE), 256, 0, stream>>>(
      x, We_t, be, cnt, aid_list, gate_list, aoutb);
  proj_gemm<<<dim3(T_TOK / 128, DIM / 128), 256, 0, stream>>>(aoutb, Wo_t, bo, x, out);
  rmsnorm_kernel<<<T_TOK, 256, 0, stream>>>(out, nw);
}

// Round 2
// 952.828 us; speedup vs baseline: 1.1589x; 1.1589x over previous
//
#include <hip/hip_runtime.h>
#include <hip/hip_bf16.h>
#include <stdint.h>

typedef __bf16 bf16;
typedef __bf16 bf16x4 __attribute__((ext_vector_type(4)));
typedef __bf16 bf16x8 __attribute__((ext_vector_type(8)));
typedef float floatx4 __attribute__((ext_vector_type(4)));

#define T_TOK 8192
#define DIM 2048
#define NE 8

// ---- async global->LDS 16B (m97 pattern). Per-lane global address OK;
//      LDS dest must be wave-uniform base + lane*16. ----
__device__ inline void gld_lds16(const bf16* g, bf16* l) {
  __builtin_amdgcn_global_load_lds(
      (const __attribute__((address_space(1))) uint32_t*)g,
      (__attribute__((address_space(3))) uint32_t*)l, 16, 0, 0);
}

// ---- transpose [Dk,Dn] fp32 -> [Dn,Dk] bf16, batched over blockIdx.z ----
__global__ __launch_bounds__(256) void transpose_convert(
    const float* __restrict__ in, bf16* __restrict__ out) {
  __shared__ float tile[32][33];
  const int tx = threadIdx.x & 31;
  const int ty = threadIdx.x >> 5;
  const int n0 = blockIdx.x * 32;
  const int k0 = blockIdx.y * 32;
  const size_t base = (size_t)blockIdx.z * DIM * DIM;
  const float* src = in + base;
  bf16* dst = out + base;
#pragma unroll
  for (int i = 0; i < 32; i += 8)
    tile[ty + i][tx] = src[(size_t)(k0 + ty + i) * DIM + n0 + tx];
  __syncthreads();
#pragma unroll
  for (int i = 0; i < 32; i += 8)
    dst[(size_t)(n0 + ty + i) * DIM + k0 + tx] = (bf16)tile[tx][ty + i];
}

// ---- router (fused x->bf16): logits, top-2 (strict >, lower index wins ties),
//      softmax gates, scatter (assign_id, gate) into per-expert lists ----
__global__ __launch_bounds__(256) void router_kernel(
    const float* __restrict__ x, const float* __restrict__ Wr,
    const float* __restrict__ br, int* __restrict__ cnt,
    int* __restrict__ aid_list, float* __restrict__ gate_list,
    bf16* __restrict__ xb) {
  const int t = blockIdx.x;
  const int tid = threadIdx.x;
  const float* xr = x + (size_t)t * DIM;
  bf16* xbr = xb + (size_t)t * DIM;
  float acc[8];
#pragma unroll
  for (int e = 0; e < 8; ++e) acc[e] = 0.f;
#pragma unroll
  for (int h = 0; h < 2; ++h) {
    const int d0 = tid * 4 + h * 1024;
    float4 xv = *(const float4*)&xr[d0];
    bf16x4 xc;
    xc[0] = (bf16)xv.x; xc[1] = (bf16)xv.y; xc[2] = (bf16)xv.z; xc[3] = (bf16)xv.w;
    *(bf16x4*)&xbr[d0] = xc;
    const float* wp = &Wr[(size_t)d0 * NE];
    float xe[4] = {xv.x, xv.y, xv.z, xv.w};
#pragma unroll
    for (int q = 0; q < 4; ++q) {
      float4 w0 = *(const float4*)&wp[q * 8];
      float4 w1 = *(const float4*)&wp[q * 8 + 4];
      acc[0] += xe[q] * w0.x; acc[1] += xe[q] * w0.y;
      acc[2] += xe[q] * w0.z; acc[3] += xe[q] * w0.w;
      acc[4] += xe[q] * w1.x; acc[5] += xe[q] * w1.y;
      acc[6] += xe[q] * w1.z; acc[7] += xe[q] * w1.w;
    }
  }
#pragma unroll
  for (int e = 0; e < 8; ++e) {
#pragma unroll
    for (int off = 32; off > 0; off >>= 1) acc[e] += __shfl_down(acc[e], off, 64);
  }
  __shared__ float red[4][8];
  const int lane = tid & 63, wid = tid >> 6;
  if (lane == 0) {
#pragma unroll
    for (int e = 0; e < 8; ++e) red[wid][e] = acc[e];
  }
  __syncthreads();
  if (tid == 0) {
    float lg[8];
#pragma unroll
    for (int e = 0; e < 8; ++e)
      lg[e] = red[0][e] + red[1][e] + red[2][e] + red[3][e] + br[e];
    int i0 = 0;
#pragma unroll
    for (int e = 1; e < 8; ++e) if (lg[e] > lg[i0]) i0 = e;
    int i1 = (i0 == 0) ? 1 : 0;
#pragma unroll
    for (int e = 0; e < 8; ++e)
      if (e != i0 && lg[e] > lg[i1]) i1 = e;
    const float g0 = 1.f / (1.f + expf(lg[i1] - lg[i0]));
    const float g1 = 1.f - g0;
    int p0 = atomicAdd(&cnt[i0], 1);
    aid_list[i0 * T_TOK + p0] = t * 2;
    gate_list[i0 * T_TOK + p0] = g0;
    int p1 = atomicAdd(&cnt[i1], 1);
    aid_list[i1 * T_TOK + p1] = t * 2 + 1;
    gate_list[i1 * T_TOK + p1] = g1;
  }
}

// ---- grouped expert GEMM (pure m97 staging): H = silu(Xg @ We[e] + be[e]) * gate
//      128x128 tile, 4 waves x 4x4 mfma 16x16x32, A gathered via gld_lds ----
__global__ __launch_bounds__(256, 2) void expert_gemm(
    const bf16* __restrict__ xb, const bf16* __restrict__ Wt,
    const float* __restrict__ be, const int* __restrict__ cnt,
    const int* __restrict__ aid_list, const float* __restrict__ gate_list,
    bf16* __restrict__ aout) {
  const int e = blockIdx.z;
  const int ne = cnt[e];
  const int m0 = blockIdx.x * 128;
  if (m0 >= ne) return;
  const int n0 = blockIdx.y * 128;
  const int tid = threadIdx.x;

  __shared__ bf16 As[128][32];
  __shared__ bf16 Bs[128][32];
  __shared__ int aidS[128];
  __shared__ float gateS[128];

  if (tid < 128) {
    const int idx = m0 + tid;
    aidS[tid] = (idx < ne) ? aid_list[e * T_TOK + idx] : 0;
    gateS[tid] = (idx < ne) ? gate_list[e * T_TOK + idx] : 0.f;
  }
  __syncthreads();

  // staging pointers (fixed per thread; only k0 advances)
  const int kq = (tid & 3) * 8;
  const int row0 = tid >> 2;         // rows 0..63   (chunks c = tid)
  const int row1 = 64 + (tid >> 2);  // rows 64..127 (chunks c = tid+256)
  const bf16* ap0 = xb + (size_t)(aidS[row0] >> 1) * DIM + kq;
  const bf16* ap1 = xb + (size_t)(aidS[row1] >> 1) * DIM + kq;
  const bf16* wbase = Wt + (size_t)e * DIM * DIM;
  const bf16* bp0 = wbase + (size_t)(n0 + row0) * DIM + kq;
  const bf16* bp1 = wbase + (size_t)(n0 + row1) * DIM + kq;
  bf16* asd0 = &As[0][0] + (size_t)tid * 8;
  bf16* asd1 = &As[0][0] + ((size_t)tid + 256) * 8;
  bf16* bsd0 = &Bs[0][0] + (size_t)tid * 8;
  bf16* bsd1 = &Bs[0][0] + ((size_t)tid + 256) * 8;

  const int lane = tid & 63, wid = tid >> 6;
  const int wr = (wid >> 1) * 64, wc = (wid & 1) * 64;
  const int quad = lane >> 4, l15 = lane & 15;

  floatx4 acc[4][4];
#pragma unroll
  for (int i = 0; i < 4; ++i)
#pragma unroll
    for (int j = 0; j < 4; ++j) acc[i][j] = (floatx4){0.f, 0.f, 0.f, 0.f};

  for (int k0 = 0; k0 < DIM; k0 += 32) {
    gld_lds16(bp0 + k0, bsd0);
    gld_lds16(bp1 + k0, bsd1);
    gld_lds16(ap0 + k0, asd0);
    gld_lds16(ap1 + k0, asd1);
    __syncthreads();

    bf16x8 af[4], bfr[4];
#pragma unroll
    for (int i = 0; i < 4; ++i)
      af[i] = *(const bf16x8*)&As[wr + i * 16 + l15][quad * 8];
#pragma unroll
    for (int j = 0; j < 4; ++j)
      bfr[j] = *(const bf16x8*)&Bs[wc + j * 16 + l15][quad * 8];
#pragma unroll
    for (int i = 0; i < 4; ++i)
#pragma unroll
      for (int j = 0; j < 4; ++j)
        acc[i][j] = __builtin_amdgcn_mfma_f32_16x16x32_bf16(af[i], bfr[j], acc[i][j], 0, 0, 0);
    __syncthreads();
  }

  // epilogue: + be, silu, * gate, scatter bf16 to assignment row
#pragma unroll
  for (int j = 0; j < 4; ++j) {
    const int col = n0 + wc + j * 16 + l15;
    const float bev = be[e * DIM + col];
#pragma unroll
    for (int i = 0; i < 4; ++i) {
#pragma unroll
      for (int r = 0; r < 4; ++r) {
        const int rl = wr + i * 16 + quad * 4 + r;
        if (m0 + rl < ne) {
          float v = acc[i][j][r] + bev;
          v = v / (1.f + __expf(-v));
          v *= gateS[rl];
          aout[(size_t)aidS[rl] * DIM + col] = (bf16)v;
        }
      }
    }
  }
}

// ---- combine slot pairs: hcomb[t] = aout[2t] + aout[2t+1] (bf16) ----
__global__ __launch_bounds__(256) void combine_kernel(
    const bf16* __restrict__ aout, bf16* __restrict__ hcomb) {
  const size_t i = ((size_t)blockIdx.x * 256 + threadIdx.x) * 8;
  const size_t row = i >> 11;          // token
  const size_t d = i & 2047;
  const bf16* a0 = aout + (row << 12) + d;
  bf16x8 u0 = *(const bf16x8*)a0;
  bf16x8 u1 = *(const bf16x8*)(a0 + DIM);
  bf16x8 s;
#pragma unroll
  for (int q = 0; q < 8; ++q) s[q] = (bf16)((float)u0[q] + (float)u1[q]);
  *(bf16x8*)&hcomb[i] = s;
}

// ---- output projection (pure m97): hcomb @ Wo + bo + x -> y (fp32) ----
__global__ __launch_bounds__(256, 2) void proj_gemm(
    const bf16* __restrict__ hcomb, const bf16* __restrict__ Wot,
    const float* __restrict__ bo, const float* __restrict__ x,
    float* __restrict__ y) {
  const int m0 = blockIdx.x * 128;
  const int n0 = blockIdx.y * 128;
  const int tid = threadIdx.x;

  __shared__ bf16 As[128][32];
  __shared__ bf16 Bs[128][32];

  const int kq = (tid & 3) * 8;
  const int row0 = tid >> 2;
  const int row1 = 64 + (tid >> 2);
  const bf16* ap0 = hcomb + (size_t)(m0 + row0) * DIM + kq;
  const bf16* ap1 = hcomb + (size_t)(m0 + row1) * DIM + kq;
  const bf16* bp0 = Wot + (size_t)(n0 + row0) * DIM + kq;
  const bf16* bp1 = Wot + (size_t)(n0 + row1) * DIM + kq;
  bf16* asd0 = &As[0][0] + (size_t)tid * 8;
  bf16* asd1 = &As[0][0] + ((size_t)tid + 256) * 8;
  bf16* bsd0 = &Bs[0][0] + (size_t)tid * 8;
  bf16* bsd1 = &Bs[0][0] + ((size_t)tid + 256) * 8;

  const int lane = tid & 63, wid = tid >> 6;
  const int wr = (wid >> 1) * 64, wc = (wid & 1) * 64;
  const int quad = lane >> 4, l15 = lane & 15;

  floatx4 acc[4][4];
#pragma unroll
  for (int i = 0; i < 4; ++i)
#pragma unroll
    for (int j = 0; j < 4; ++j) acc[i][j] = (floatx4){0.f, 0.f, 0.f, 0.f};

  for (int k0 = 0; k0 < DIM; k0 += 32) {
    gld_lds16(bp0 + k0, bsd0);
    gld_lds16(bp1 + k0, bsd1);
    gld_lds16(ap0 + k0, asd0);
    gld_lds16(ap1 + k0, asd1);
    __syncthreads();

    bf16x8 af[4], bfr[4];
#pragma unroll
    for (int i = 0; i < 4; ++i)
      af[i] = *(const bf16x8*)&As[wr + i * 16 + l15][quad * 8];
#pragma unroll
    for (int j = 0; j < 4; ++j)
      bfr[j] = *(const bf16x8*)&Bs[wc + j * 16 + l15][quad * 8];
#pragma unroll
    for (int i = 0; i < 4; ++i)
#pragma unroll
      for (int j = 0; j < 4; ++j)
        acc[i][j] = __builtin_amdgcn_mfma_f32_16x16x32_bf16(af[i], bfr[j], acc[i][j], 0, 0, 0);
    __syncthreads();
  }

#pragma unroll
  for (int j = 0; j < 4; ++j) {
    const int col = n0 + wc + j * 16 + l15;
    const float bov = bo[col];
#pragma unroll
    for (int i = 0; i < 4; ++i) {
#pragma unroll
      for (int r = 0; r < 4; ++r) {
        const int rl = wr + i * 16 + quad * 4 + r;
        const size_t o = (size_t)(m0 + rl) * DIM + col;
        y[o] = acc[i][j][r] + bov + x[o];
      }
    }
  }
}

// ---- in-place RMSNorm over rows of d_out ----
__global__ __launch_bounds__(256) void rmsnorm_kernel(
    float* __restrict__ y, const float* __restrict__ w) {
  const int row = blockIdx.x;
  const int tid = threadIdx.x;
  float* yr = y + (size_t)row * DIM;
  float4 v0 = ((const float4*)yr)[tid];
  float4 v1 = ((const float4*)yr)[tid + 256];
  float ss = v0.x * v0.x + v0.y * v0.y + v0.z * v0.z + v0.w * v0.w +
             v1.x * v1.x + v1.y * v1.y + v1.z * v1.z + v1.w * v1.w;
#pragma unroll
  for (int off = 32; off > 0; off >>= 1) ss += __shfl_down(ss, off, 64);
  __shared__ float s4[4];
  const int lane = tid & 63, wid = tid >> 6;
  if (lane == 0) s4[wid] = ss;
  __syncthreads();
  const float tot = s4[0] + s4[1] + s4[2] + s4[3];
  const float r = rsqrtf(tot / (float)DIM + 1e-6f);
  float4 w0 = ((const float4*)w)[tid];
  float4 w1 = ((const float4*)w)[tid + 256];
  float4 o0 = make_float4(v0.x * r * w0.x, v0.y * r * w0.y, v0.z * r * w0.z, v0.w * r * w0.w);
  float4 o1 = make_float4(v1.x * r * w1.x, v1.y * r * w1.y, v1.z * r * w1.z, v1.w * r * w1.w);
  ((float4*)yr)[tid] = o0;
  ((float4*)yr)[tid + 256] = o1;
}

extern "C" void kernel_launch(void* const* d_in, const int* in_sizes, int n_in,
                              void* d_out, int out_size, void* d_ws, size_t ws_size,
                              hipStream_t stream) {
  const float* x  = (const float*)d_in[0];
  const float* Wr = (const float*)d_in[1];
  const float* br = (const float*)d_in[2];
  const float* We = (const float*)d_in[3];
  const float* be = (const float*)d_in[4];
  const float* Wo = (const float*)d_in[5];
  const float* bo = (const float*)d_in[6];
  const float* nw = (const float*)d_in[7];
  float* out = (float*)d_out;

  uint8_t* ws = (uint8_t*)d_ws;
  size_t off = 0;
  auto carve = [&](size_t bytes) -> void* {
    void* p = ws + off;
    off += (bytes + 255) & ~(size_t)255;
    return p;
  };
  int*   cnt       = (int*)carve(NE * sizeof(int));
  int*   aid_list  = (int*)carve((size_t)NE * T_TOK * sizeof(int));
  float* gate_list = (float*)carve((size_t)NE * T_TOK * sizeof(float));
  bf16*  We_t      = (bf16*)carve((size_t)NE * DIM * DIM * sizeof(bf16));
  bf16*  Wo_t      = (bf16*)carve((size_t)DIM * DIM * sizeof(bf16));
  bf16*  aoutb     = (bf16*)carve((size_t)T_TOK * 2 * DIM * sizeof(bf16));
  bf16*  xb        = (bf16*)carve((size_t)T_TOK * DIM * sizeof(bf16));
  // hcomb aliases We_t: We_t is dead once expert_gemm completes, and
  // combine/proj run strictly after it on the same stream.
  bf16*  hcomb     = We_t;
  (void)ws_size; (void)in_sizes; (void)n_in; (void)out_size;

  hipMemsetAsync(cnt, 0, NE * sizeof(int), stream);
  transpose_convert<<<dim3(DIM / 32, DIM / 32, NE), 256, 0, stream>>>(We, We_t);
  transpose_convert<<<dim3(DIM / 32, DIM / 32, 1), 256, 0, stream>>>(Wo, Wo_t);
  router_kernel<<<T_TOK, 256, 0, stream>>>(x, Wr, br, cnt, aid_list, gate_list, xb);
  expert_gemm<<<dim3(T_TOK / 128, DIM / 128, NE), 256, 0, stream>>>(
      xb, We_t, be, cnt, aid_list, gate_list, aoutb);
  combine_kernel<<<(T_TOK * DIM / 8) / 256, 256, 0, stream>>>(aoutb, hcomb);
  proj_gemm<<<dim3(T_TOK / 128, DIM / 128), 256, 0, stream>>>(hcomb, Wo_t, bo, x, out);
  rmsnorm_kernel<<<T_TOK, 256, 0, stream>>>(out, nw);
}

// Round 3
// 838.912 us; speedup vs baseline: 1.3163x; 1.1358x over previous
//
#include <hip/hip_runtime.h>
#include <hip/hip_bf16.h>
#include <stdint.h>

typedef __bf16 bf16;
typedef __bf16 bf16x4 __attribute__((ext_vector_type(4)));
typedef __bf16 bf16x8 __attribute__((ext_vector_type(8)));
typedef float floatx4 __attribute__((ext_vector_type(4)));

#define T_TOK 8192
#define DIM 2048
#define NE 8
#define MAX_CHUNKS 136

// ---- async global->LDS 16B. Per-lane global address free; LDS dest is
//      wave-uniform base + lane*16 (our chunk ids are wavebase+lane). ----
__device__ inline void gld_lds16(const bf16* g, bf16* l) {
  __builtin_amdgcn_global_load_lds(
      (const __attribute__((address_space(1))) uint32_t*)g,
      (__attribute__((address_space(3))) uint32_t*)l, 16, 0, 0);
}

// ---- transpose [Dk,Dn] fp32 -> [Dn,Dk] bf16, batched over blockIdx.z ----
__global__ __launch_bounds__(256) void transpose_convert(
    const float* __restrict__ in, bf16* __restrict__ out) {
  __shared__ float tile[32][33];
  const int tx = threadIdx.x & 31;
  const int ty = threadIdx.x >> 5;
  const int n0 = blockIdx.x * 32;
  const int k0 = blockIdx.y * 32;
  const size_t base = (size_t)blockIdx.z * DIM * DIM;
  const float* src = in + base;
  bf16* dst = out + base;
#pragma unroll
  for (int i = 0; i < 32; i += 8)
    tile[ty + i][tx] = src[(size_t)(k0 + ty + i) * DIM + n0 + tx];
  __syncthreads();
#pragma unroll
  for (int i = 0; i < 32; i += 8)
    dst[(size_t)(n0 + ty + i) * DIM + k0 + tx] = (bf16)tile[tx][ty + i];
}

// ---- router (fused x->bf16): logits, top-2 (strict >, lower idx wins ties),
//      softmax gates, scatter (assign_id, gate) into per-expert lists ----
__global__ __launch_bounds__(256) void router_kernel(
    const float* __restrict__ x, const float* __restrict__ Wr,
    const float* __restrict__ br, int* __restrict__ cnt,
    int* __restrict__ aid_list, float* __restrict__ gate_list,
    bf16* __restrict__ xb) {
  const int t = blockIdx.x;
  const int tid = threadIdx.x;
  const float* xr = x + (size_t)t * DIM;
  bf16* xbr = xb + (size_t)t * DIM;
  float acc[8];
#pragma unroll
  for (int e = 0; e < 8; ++e) acc[e] = 0.f;
#pragma unroll
  for (int h = 0; h < 2; ++h) {
    const int d0 = tid * 4 + h * 1024;
    float4 xv = *(const float4*)&xr[d0];
    bf16x4 xc;
    xc[0] = (bf16)xv.x; xc[1] = (bf16)xv.y; xc[2] = (bf16)xv.z; xc[3] = (bf16)xv.w;
    *(bf16x4*)&xbr[d0] = xc;
    const float* wp = &Wr[(size_t)d0 * NE];
    float xe[4] = {xv.x, xv.y, xv.z, xv.w};
#pragma unroll
    for (int q = 0; q < 4; ++q) {
      float4 w0 = *(const float4*)&wp[q * 8];
      float4 w1 = *(const float4*)&wp[q * 8 + 4];
      acc[0] += xe[q] * w0.x; acc[1] += xe[q] * w0.y;
      acc[2] += xe[q] * w0.z; acc[3] += xe[q] * w0.w;
      acc[4] += xe[q] * w1.x; acc[5] += xe[q] * w1.y;
      acc[6] += xe[q] * w1.z; acc[7] += xe[q] * w1.w;
    }
  }
#pragma unroll
  for (int e = 0; e < 8; ++e) {
#pragma unroll
    for (int off = 32; off > 0; off >>= 1) acc[e] += __shfl_down(acc[e], off, 64);
  }
  __shared__ float red[4][8];
  const int lane = tid & 63, wid = tid >> 6;
  if (lane == 0) {
#pragma unroll
    for (int e = 0; e < 8; ++e) red[wid][e] = acc[e];
  }
  __syncthreads();
  if (tid == 0) {
    float lg[8];
#pragma unroll
    for (int e = 0; e < 8; ++e)
      lg[e] = red[0][e] + red[1][e] + red[2][e] + red[3][e] + br[e];
    int i0 = 0;
#pragma unroll
    for (int e = 1; e < 8; ++e) if (lg[e] > lg[i0]) i0 = e;
    int i1 = (i0 == 0) ? 1 : 0;
#pragma unroll
    for (int e = 0; e < 8; ++e)
      if (e != i0 && lg[e] > lg[i1]) i1 = e;
    const float g0 = 1.f / (1.f + expf(lg[i1] - lg[i0]));
    const float g1 = 1.f - g0;
    int p0 = atomicAdd(&cnt[i0], 1);
    aid_list[i0 * T_TOK + p0] = t * 2;
    gate_list[i0 * T_TOK + p0] = g0;
    int p1 = atomicAdd(&cnt[i1], 1);
    aid_list[i1 * T_TOK + p1] = t * 2 + 1;
    gate_list[i1 * T_TOK + p1] = g1;
  }
}

// ---- build compact (expert, m0) chunk table from per-expert counts ----
__global__ void build_chunks(const int* __restrict__ cnt, int2* __restrict__ chunks,
                             int* __restrict__ nchunks) {
  if (threadIdx.x == 0 && blockIdx.x == 0) {
    int tot = 0;
#pragma unroll
    for (int e = 0; e < NE; ++e) {
      const int ne = cnt[e];
      for (int m0 = 0; m0 < ne; m0 += 128) chunks[tot++] = make_int2(e, m0);
    }
    *nchunks = tot;
  }
}

// ===========================================================================
// BK=64 GEMM core. LDS tiles [128 rows][64 k] bf16, stored in 16B chunks with
// XOR swizzle: chunk c (0..1023) holds row r=c>>3, k-block kb=(c&7)^(r&7).
// Fragment read of (row, kb): offset = row*64 + ((kb^(row&7))*8) elems.
// -> 16 lanes of a quad spread over 8 bank-groups, 2 lanes each = conflict-free.
// ===========================================================================

// ---- grouped expert GEMM: H = silu(Xg @ We[e]^T-layout + be[e]) * gate ----
__global__ __launch_bounds__(256, 2) void expert_gemm(
    const bf16* __restrict__ xb, const bf16* __restrict__ Wt,
    const float* __restrict__ be, const int* __restrict__ cnt,
    const int* __restrict__ aid_list, const float* __restrict__ gate_list,
    const int2* __restrict__ chunks, const int* __restrict__ nchunks,
    bf16* __restrict__ aout) {
  const int cid = blockIdx.x;
  if (cid >= *nchunks) return;
  const int2 ch = chunks[cid];
  const int e = ch.x;
  const int m0 = ch.y;
  const int ne = cnt[e];
  const int n0 = blockIdx.y * 128;
  const int tid = threadIdx.x;

  __shared__ bf16 As[128][64];
  __shared__ bf16 Bs[128][64];
  __shared__ int aidS[128];
  __shared__ float gateS[128];

  if (tid < 128) {
    const int idx = m0 + tid;
    aidS[tid] = (idx < ne) ? aid_list[e * T_TOK + idx] : 0;
    gateS[tid] = (idx < ne) ? gate_list[e * T_TOK + idx] : 0.f;
  }
  __syncthreads();

  // staging: thread covers chunks {tid, tid+256, tid+512, tid+768}
  const int r0 = tid >> 3;                              // base row (0..31)
  const int kq = (((tid & 7) ^ (r0 & 7))) * 8;          // swizzled k offset
  const bf16* wbase = Wt + (size_t)e * DIM * DIM;
  const bf16* ap[4];
  const bf16* bp[4];
#pragma unroll
  for (int h = 0; h < 4; ++h) {
    const int r = r0 + 32 * h;
    ap[h] = xb + (size_t)(aidS[r] >> 1) * DIM + kq;
    bp[h] = wbase + (size_t)(n0 + r) * DIM + kq;
  }
  bf16* const asF = &As[0][0];
  bf16* const bsF = &Bs[0][0];

  const int lane = tid & 63, wid = tid >> 6;
  const int wr = (wid >> 1) * 64, wc = (wid & 1) * 64;
  const int quad = lane >> 4, l15 = lane & 15;

  floatx4 acc[4][4];
#pragma unroll
  for (int i = 0; i < 4; ++i)
#pragma unroll
    for (int j = 0; j < 4; ++j) acc[i][j] = (floatx4){0.f, 0.f, 0.f, 0.f};

  // fragment LDS offsets (loop-invariant)
  int aoff[2][4], boff[2][4];
#pragma unroll
  for (int s = 0; s < 2; ++s) {
    const int kb = s * 4 + quad;
#pragma unroll
    for (int i = 0; i < 4; ++i) {
      const int mi = wr + i * 16 + l15;
      aoff[s][i] = mi * 64 + ((kb ^ (mi & 7)) * 8);
      const int nj = wc + i * 16 + l15;
      boff[s][i] = nj * 64 + ((kb ^ (nj & 7)) * 8);
    }
  }

  for (int k0 = 0; k0 < DIM; k0 += 64) {
#pragma unroll
    for (int h = 0; h < 4; ++h) {
      gld_lds16(bp[h] + k0, bsF + ((size_t)tid + 256 * h) * 8);
      gld_lds16(ap[h] + k0, asF + ((size_t)tid + 256 * h) * 8);
    }
    __syncthreads();

#pragma unroll
    for (int s = 0; s < 2; ++s) {
      bf16x8 af[4], bfr[4];
#pragma unroll
      for (int i = 0; i < 4; ++i) af[i] = *(const bf16x8*)&asF[aoff[s][i]];
#pragma unroll
      for (int j = 0; j < 4; ++j) bfr[j] = *(const bf16x8*)&bsF[boff[s][j]];
#pragma unroll
      for (int i = 0; i < 4; ++i)
#pragma unroll
        for (int j = 0; j < 4; ++j)
          acc[i][j] = __builtin_amdgcn_mfma_f32_16x16x32_bf16(af[i], bfr[j], acc[i][j], 0, 0, 0);
    }
    __syncthreads();
  }

  // epilogue: + be, silu, * gate, scatter bf16 to assignment row
#pragma unroll
  for (int j = 0; j < 4; ++j) {
    const int col = n0 + wc + j * 16 + l15;
    const float bev = be[e * DIM + col];
#pragma unroll
    for (int i = 0; i < 4; ++i) {
#pragma unroll
      for (int r = 0; r < 4; ++r) {
        const int rl = wr + i * 16 + quad * 4 + r;
        if (m0 + rl < ne) {
          float v = acc[i][j][r] + bev;
          v = v / (1.f + __expf(-v));
          v *= gateS[rl];
          aout[(size_t)aidS[rl] * DIM + col] = (bf16)v;
        }
      }
    }
  }
}

// ---- combine slot pairs: hcomb[t] = aout[2t] + aout[2t+1] (bf16) ----
__global__ __launch_bounds__(256) void combine_kernel(
    const bf16* __restrict__ aout, bf16* __restrict__ hcomb) {
  const size_t i = ((size_t)blockIdx.x * 256 + threadIdx.x) * 8;
  const size_t row = i >> 11;
  const size_t d = i & 2047;
  const bf16* a0 = aout + (row << 12) + d;
  bf16x8 u0 = *(const bf16x8*)a0;
  bf16x8 u1 = *(const bf16x8*)(a0 + DIM);
  bf16x8 s;
#pragma unroll
  for (int q = 0; q < 8; ++q) s[q] = (bf16)((float)u0[q] + (float)u1[q]);
  *(bf16x8*)&hcomb[i] = s;
}

// ---- output projection: hcomb @ Wo + bo + x -> y (fp32), BK=64 core ----
__global__ __launch_bounds__(256, 2) void proj_gemm(
    const bf16* __restrict__ hcomb, const bf16* __restrict__ Wot,
    const float* __restrict__ bo, const float* __restrict__ x,
    float* __restrict__ y) {
  const int m0 = blockIdx.x * 128;
  const int n0 = blockIdx.y * 128;
  const int tid = threadIdx.x;

  __shared__ bf16 As[128][64];
  __shared__ bf16 Bs[128][64];

  const int r0 = tid >> 3;
  const int kq = (((tid & 7) ^ (r0 & 7))) * 8;
  const bf16* ap[4];
  const bf16* bp[4];
#pragma unroll
  for (int h = 0; h < 4; ++h) {
    const int r = r0 + 32 * h;
    ap[h] = hcomb + (size_t)(m0 + r) * DIM + kq;
    bp[h] = Wot + (size_t)(n0 + r) * DIM + kq;
  }
  bf16* const asF = &As[0][0];
  bf16* const bsF = &Bs[0][0];

  const int lane = tid & 63, wid = tid >> 6;
  const int wr = (wid >> 1) * 64, wc = (wid & 1) * 64;
  const int quad = lane >> 4, l15 = lane & 15;

  floatx4 acc[4][4];
#pragma unroll
  for (int i = 0; i < 4; ++i)
#pragma unroll
    for (int j = 0; j < 4; ++j) acc[i][j] = (floatx4){0.f, 0.f, 0.f, 0.f};

  int aoff[2][4], boff[2][4];
#pragma unroll
  for (int s = 0; s < 2; ++s) {
    const int kb = s * 4 + quad;
#pragma unroll
    for (int i = 0; i < 4; ++i) {
      const int mi = wr + i * 16 + l15;
      aoff[s][i] = mi * 64 + ((kb ^ (mi & 7)) * 8);
      const int nj = wc + i * 16 + l15;
      boff[s][i] = nj * 64 + ((kb ^ (nj & 7)) * 8);
    }
  }

  for (int k0 = 0; k0 < DIM; k0 += 64) {
#pragma unroll
    for (int h = 0; h < 4; ++h) {
      gld_lds16(bp[h] + k0, bsF + ((size_t)tid + 256 * h) * 8);
      gld_lds16(ap[h] + k0, asF + ((size_t)tid + 256 * h) * 8);
    }
    __syncthreads();

#pragma unroll
    for (int s = 0; s < 2; ++s) {
      bf16x8 af[4], bfr[4];
#pragma unroll
      for (int i = 0; i < 4; ++i) af[i] = *(const bf16x8*)&asF[aoff[s][i]];
#pragma unroll
      for (int j = 0; j < 4; ++j) bfr[j] = *(const bf16x8*)&bsF[boff[s][j]];
#pragma unroll
      for (int i = 0; i < 4; ++i)
#pragma unroll
        for (int j = 0; j < 4; ++j)
          acc[i][j] = __builtin_amdgcn_mfma_f32_16x16x32_bf16(af[i], bfr[j], acc[i][j], 0, 0, 0);
    }
    __syncthreads();
  }

#pragma unroll
  for (int j = 0; j < 4; ++j) {
    const int col = n0 + wc + j * 16 + l15;
    const float bov = bo[col];
#pragma unroll
    for (int i = 0; i < 4; ++i) {
#pragma unroll
      for (int r = 0; r < 4; ++r) {
        const int rl = wr + i * 16 + quad * 4 + r;
        const size_t o = (size_t)(m0 + rl) * DIM + col;
        y[o] = acc[i][j][r] + bov + x[o];
      }
    }
  }
}

// ---- in-place RMSNorm over rows of d_out ----
__global__ __launch_bounds__(256) void rmsnorm_kernel(
    float* __restrict__ y, const float* __restrict__ w) {
  const int row = blockIdx.x;
  const int tid = threadIdx.x;
  float* yr = y + (size_t)row * DIM;
  float4 v0 = ((const float4*)yr)[tid];
  float4 v1 = ((const float4*)yr)[tid + 256];
  float ss = v0.x * v0.x + v0.y * v0.y + v0.z * v0.z + v0.w * v0.w +
             v1.x * v1.x + v1.y * v1.y + v1.z * v1.z + v1.w * v1.w;
#pragma unroll
  for (int off = 32; off > 0; off >>= 1) ss += __shfl_down(ss, off, 64);
  __shared__ float s4[4];
  const int lane = tid & 63, wid = tid >> 6;
  if (lane == 0) s4[wid] = ss;
  __syncthreads();
  const float tot = s4[0] + s4[1] + s4[2] + s4[3];
  const float r = rsqrtf(tot / (float)DIM + 1e-6f);
  float4 w0 = ((const float4*)w)[tid];
  float4 w1 = ((const float4*)w)[tid + 256];
  float4 o0 = make_float4(v0.x * r * w0.x, v0.y * r * w0.y, v0.z * r * w0.z, v0.w * r * w0.w);
  float4 o1 = make_float4(v1.x * r * w1.x, v1.y * r * w1.y, v1.z * r * w1.z, v1.w * r * w1.w);
  ((float4*)yr)[tid] = o0;
  ((float4*)yr)[tid + 256] = o1;
}

extern "C" void kernel_launch(void* const* d_in, const int* in_sizes, int n_in,
                              void* d_out, int out_size, void* d_ws, size_t ws_size,
                              hipStream_t stream) {
  const float* x  = (const float*)d_in[0];
  const float* Wr = (const float*)d_in[1];
  const float* br = (const float*)d_in[2];
  const float* We = (const float*)d_in[3];
  const float* be = (const float*)d_in[4];
  const float* Wo = (const float*)d_in[5];
  const float* bo = (const float*)d_in[6];
  const float* nw = (const float*)d_in[7];
  float* out = (float*)d_out;

  uint8_t* ws = (uint8_t*)d_ws;
  size_t off = 0;
  auto carve = [&](size_t bytes) -> void* {
    void* p = ws + off;
    off += (bytes + 255) & ~(size_t)255;
    return p;
  };
  int*   cnt       = (int*)carve(NE * sizeof(int));
  int*   aid_list  = (int*)carve((size_t)NE * T_TOK * sizeof(int));
  float* gate_list = (float*)carve((size_t)NE * T_TOK * sizeof(float));
  int2*  chunks    = (int2*)carve(MAX_CHUNKS * sizeof(int2));
  int*   nchunks   = (int*)carve(sizeof(int));
  bf16*  We_t      = (bf16*)carve((size_t)NE * DIM * DIM * sizeof(bf16));
  bf16*  Wo_t      = (bf16*)carve((size_t)DIM * DIM * sizeof(bf16));
  bf16*  aoutb     = (bf16*)carve((size_t)T_TOK * 2 * DIM * sizeof(bf16));
  bf16*  xb        = (bf16*)carve((size_t)T_TOK * DIM * sizeof(bf16));
  // hcomb aliases We_t: dead after expert_gemm; combine/proj run strictly later.
  bf16*  hcomb     = We_t;
  (void)ws_size; (void)in_sizes; (void)n_in; (void)out_size;

  hipMemsetAsync(cnt, 0, NE * sizeof(int), stream);
  transpose_convert<<<dim3(DIM / 32, DIM / 32, NE), 256, 0, stream>>>(We, We_t);
  transpose_convert<<<dim3(DIM / 32, DIM / 32, 1), 256, 0, stream>>>(Wo, Wo_t);
  router_kernel<<<T_TOK, 256, 0, stream>>>(x, Wr, br, cnt, aid_list, gate_list, xb);
  build_chunks<<<1, 64, 0, stream>>>(cnt, chunks, nchunks);
  expert_gemm<<<dim3(MAX_CHUNKS, DIM / 128), 256, 0, stream>>>(
      xb, We_t, be, cnt, aid_list, gate_list, chunks, nchunks, aoutb);
  combine_kernel<<<(T_TOK * DIM / 8) / 256, 256, 0, stream>>>(aoutb, hcomb);
  proj_gemm<<<dim3(T_TOK / 128, DIM / 128), 256, 0, stream>>>(hcomb, Wo_t, bo, x, out);
  rmsnorm_kernel<<<T_TOK, 256, 0, stream>>>(out, nw);
}